// Round 7
// baseline (398.590 us; speedup 1.0000x reference)
//
#include <hip/hip_runtime.h>

#define CLS 6

constexpr int HIST_BLOCKS  = 2048;
constexpr int HIST_THREADS = 256;
constexpr int NCOPY        = 4;    // replicated LDS histograms
constexpr int CM_STRIDE    = 40;   // 36 buckets padded to 40 words

__device__ __forceinline__ int argmax6(float v0, float v1, float v2,
                                       float v3, float v4, float v5) {
    int   pr = 0; float m = v0;
    if (v1 > m) { m = v1; pr = 1; }
    if (v2 > m) { m = v2; pr = 2; }
    if (v3 > m) { m = v3; pr = 3; }
    if (v4 > m) { m = v4; pr = 4; }
    if (v5 > m) { m = v5; pr = 5; }
    return pr;
}

// ws layout: cm[0..35] counts, ws[36] = ticket. memset'd to 0 before launch.
__global__ __launch_bounds__(HIST_THREADS)
void macro_fused_kernel(const float* __restrict__ inputs,
                        const int*   __restrict__ targets,
                        const float* __restrict__ wts,
                        unsigned int* __restrict__ cm,      // 36 words
                        unsigned int* __restrict__ ticket,  // 1 word
                        float* __restrict__ out,
                        long long n_rows) {
    __shared__ unsigned int cm_s[NCOPY * CM_STRIDE];
    __shared__ bool is_last;
    const int tid = threadIdx.x;
    if (tid < NCOPY * CM_STRIDE) cm_s[tid] = 0u;
    __syncthreads();

    const float w0 = wts[0], w1 = wts[1], w2 = wts[2];
    const float w3 = wts[3], w4 = wts[4], w5 = wts[5];

    const float4* __restrict__ in4 = (const float4*)inputs;
    const int4*   __restrict__ tg4 = (const int4*)targets;

    const int copy_base = (tid & (NCOPY - 1)) * CM_STRIDE;

    const long long n_quads = n_rows >> 2;                 // 4 rows per thread-iter
    const long long stride  = (long long)gridDim.x * blockDim.x;

    for (long long q = (long long)blockIdx.x * blockDim.x + tid;
         q < n_quads; q += stride) {
        // rows 4q..4q+3 : 96 bytes = 6 aligned float4; targets: 1 int4
        const long long b = 6 * q;
        float4 f0 = in4[b + 0];
        float4 f1 = in4[b + 1];
        float4 f2 = in4[b + 2];
        float4 f3 = in4[b + 3];
        float4 f4 = in4[b + 4];
        float4 f5 = in4[b + 5];
        int4   t  = tg4[q];

        int p0 = argmax6(f0.x * w0, f0.y * w1, f0.z * w2, f0.w * w3, f1.x * w4, f1.y * w5);
        int p1 = argmax6(f1.z * w0, f1.w * w1, f2.x * w2, f2.y * w3, f2.z * w4, f2.w * w5);
        int p2 = argmax6(f3.x * w0, f3.y * w1, f3.z * w2, f3.w * w3, f4.x * w4, f4.y * w5);
        int p3 = argmax6(f4.z * w0, f4.w * w1, f5.x * w2, f5.y * w3, f5.z * w4, f5.w * w5);

        atomicAdd(&cm_s[copy_base + p0 * CLS + t.x], 1u);
        atomicAdd(&cm_s[copy_base + p1 * CLS + t.y], 1u);
        atomicAdd(&cm_s[copy_base + p2 * CLS + t.z], 1u);
        atomicAdd(&cm_s[copy_base + p3 * CLS + t.w], 1u);
    }

    // tail rows (n_rows % 4); N=8388608 -> none, kept for generality
    if (blockIdx.x == 0 && tid == 0) {
        for (long long r = (n_quads << 2); r < n_rows; ++r) {
            int pr = argmax6(inputs[r * CLS + 0] * w0, inputs[r * CLS + 1] * w1,
                             inputs[r * CLS + 2] * w2, inputs[r * CLS + 3] * w3,
                             inputs[r * CLS + 4] * w4, inputs[r * CLS + 5] * w5);
            atomicAdd(&cm_s[pr * CLS + targets[r]], 1u);
        }
    }

    __syncthreads();
    // flush block-partial to global cm (device-scope atomics by default)
    if (tid < CLS * CLS) {
        unsigned int v = cm_s[tid]
                       + cm_s[CM_STRIDE + tid]
                       + cm_s[2 * CM_STRIDE + tid]
                       + cm_s[3 * CM_STRIDE + tid];
        if (v) atomicAdd(&cm[tid], v);
    }

    // class_weight passthrough output — any block, same value every call
    if (blockIdx.x == 0 && tid < CLS) out[1 + tid] = wts[tid];

    // last-block-done election
    __syncthreads();                 // all lanes' cm atomics issued & drained
    if (tid == 0) {
        __threadfence();             // device-scope release before ticket
        unsigned int prev = atomicAdd(ticket, 1u);
        is_last = (prev == (unsigned int)(gridDim.x - 1));
    }
    __syncthreads();

    if (is_last) {
        // acquire: read counts through the coherent atomic path
        if (tid < CLS * CLS) cm_s[tid] = atomicAdd(&cm[tid], 0u);
        __syncthreads();
        if (tid == 0) {
            float c[CLS * CLS];
            #pragma unroll
            for (int i = 0; i < CLS * CLS; ++i) c[i] = (float)cm_s[i];
            float f1sum = 0.0f;
            #pragma unroll
            for (int i = 0; i < CLS; ++i) {
                float col = 0.0f, row = 0.0f;
                #pragma unroll
                for (int j = 0; j < CLS; ++j) {
                    col += c[j * CLS + i];   // cm.sum(axis=0)[i]
                    row += c[i * CLS + j];   // cm.sum(axis=1)[i]
                }
                float d  = c[i * CLS + i];
                float pr = d / col;
                float rc = d / row;
                f1sum += 2.0f * pr * rc / (pr + rc);
            }
            out[0] = -(f1sum / (float)CLS);
        }
    }
}

extern "C" void kernel_launch(void* const* d_in, const int* in_sizes, int n_in,
                              void* d_out, int out_size, void* d_ws, size_t ws_size,
                              hipStream_t stream) {
    const float* inputs  = (const float*)d_in[0];
    const int*   targets = (const int*)d_in[1];
    const float* wts     = (const float*)d_in[2];
    float*       out     = (float*)d_out;
    unsigned int* cm     = (unsigned int*)d_ws;
    unsigned int* ticket = cm + CLS * CLS;

    const long long n_rows = (long long)in_sizes[0] / CLS;

    hipMemsetAsync(d_ws, 0, (CLS * CLS + 1) * sizeof(unsigned int), stream);
    macro_fused_kernel<<<HIST_BLOCKS, HIST_THREADS, 0, stream>>>(
        inputs, targets, wts, cm, ticket, out, n_rows);
}

// Round 8
// 299.471 us; speedup vs baseline: 1.3310x; 1.3310x over previous
//
#include <hip/hip_runtime.h>

#define CLS 6

constexpr int HIST_BLOCKS  = 2048;
constexpr int HIST_THREADS = 256;
constexpr int NCOPY        = 4;    // replicated LDS histograms
constexpr int CM_STRIDE    = 40;   // 36 buckets padded to 40 words

__device__ __forceinline__ int argmax6(float v0, float v1, float v2,
                                       float v3, float v4, float v5) {
    int   pr = 0; float m = v0;
    if (v1 > m) { m = v1; pr = 1; }
    if (v2 > m) { m = v2; pr = 2; }
    if (v3 > m) { m = v3; pr = 3; }
    if (v4 > m) { m = v4; pr = 4; }
    if (v5 > m) { m = v5; pr = 5; }
    return pr;
}

__global__ __launch_bounds__(HIST_THREADS, 8)
void cm_hist_kernel(const float* __restrict__ inputs,
                    const int*   __restrict__ targets,
                    const float* __restrict__ wts,
                    unsigned int* __restrict__ cm,
                    long long n_rows) {
    __shared__ unsigned int cm_s[NCOPY * CM_STRIDE];
    const int tid = threadIdx.x;
    if (tid < NCOPY * CM_STRIDE) cm_s[tid] = 0u;
    __syncthreads();

    const float w0 = wts[0], w1 = wts[1], w2 = wts[2];
    const float w3 = wts[3], w4 = wts[4], w5 = wts[5];

    const float4* __restrict__ in4 = (const float4*)inputs;
    const int4*   __restrict__ tg4 = (const int4*)targets;

    const int copy_base = (tid & (NCOPY - 1)) * CM_STRIDE;

    const long long n_quads = n_rows >> 2;                 // 4 rows per thread-iter
    const long long stride  = (long long)gridDim.x * blockDim.x;

    for (long long q = (long long)blockIdx.x * blockDim.x + tid;
         q < n_quads; q += stride) {
        // rows 4q..4q+3 : 96 bytes = 6 aligned float4; targets: 1 int4
        const long long b = 6 * q;
        float4 f0 = in4[b + 0];
        float4 f1 = in4[b + 1];
        float4 f2 = in4[b + 2];
        float4 f3 = in4[b + 3];
        float4 f4 = in4[b + 4];
        float4 f5 = in4[b + 5];
        int4   t  = tg4[q];

        int p0 = argmax6(f0.x * w0, f0.y * w1, f0.z * w2, f0.w * w3, f1.x * w4, f1.y * w5);
        int p1 = argmax6(f1.z * w0, f1.w * w1, f2.x * w2, f2.y * w3, f2.z * w4, f2.w * w5);
        int p2 = argmax6(f3.x * w0, f3.y * w1, f3.z * w2, f3.w * w3, f4.x * w4, f4.y * w5);
        int p3 = argmax6(f4.z * w0, f4.w * w1, f5.x * w2, f5.y * w3, f5.z * w4, f5.w * w5);

        atomicAdd(&cm_s[copy_base + p0 * CLS + t.x], 1u);
        atomicAdd(&cm_s[copy_base + p1 * CLS + t.y], 1u);
        atomicAdd(&cm_s[copy_base + p2 * CLS + t.z], 1u);
        atomicAdd(&cm_s[copy_base + p3 * CLS + t.w], 1u);
    }

    // tail rows (n_rows % 4); N=8388608 -> none, kept for generality
    if (blockIdx.x == 0 && tid == 0) {
        for (long long r = (n_quads << 2); r < n_rows; ++r) {
            int pr = argmax6(inputs[r * CLS + 0] * w0, inputs[r * CLS + 1] * w1,
                             inputs[r * CLS + 2] * w2, inputs[r * CLS + 3] * w3,
                             inputs[r * CLS + 4] * w4, inputs[r * CLS + 5] * w5);
            atomicAdd(&cm_s[pr * CLS + targets[r]], 1u);
        }
    }

    __syncthreads();
    if (tid < CLS * CLS) {
        unsigned int v = cm_s[tid]
                       + cm_s[CM_STRIDE + tid]
                       + cm_s[2 * CM_STRIDE + tid]
                       + cm_s[3 * CM_STRIDE + tid];
        if (v) atomicAdd(&cm[tid], v);   // device-scope by default; no fence needed
    }
}

__global__ void macro_score_kernel(const unsigned int* __restrict__ cm,
                                   const float* __restrict__ wts,
                                   float* __restrict__ out) {
    if (threadIdx.x == 0) {
        float c[CLS * CLS];
        #pragma unroll
        for (int i = 0; i < CLS * CLS; ++i) c[i] = (float)cm[i];
        float f1sum = 0.0f;
        #pragma unroll
        for (int i = 0; i < CLS; ++i) {
            float col = 0.0f, row = 0.0f;
            #pragma unroll
            for (int j = 0; j < CLS; ++j) {
                col += c[j * CLS + i];   // cm.sum(axis=0)[i]
                row += c[i * CLS + j];   // cm.sum(axis=1)[i]
            }
            float d  = c[i * CLS + i];
            float pr = d / col;
            float rc = d / row;
            f1sum += 2.0f * pr * rc / (pr + rc);
        }
        out[0] = -(f1sum / (float)CLS);
    }
    if (threadIdx.x < CLS) out[1 + threadIdx.x] = wts[threadIdx.x];
}

extern "C" void kernel_launch(void* const* d_in, const int* in_sizes, int n_in,
                              void* d_out, int out_size, void* d_ws, size_t ws_size,
                              hipStream_t stream) {
    const float* inputs  = (const float*)d_in[0];
    const int*   targets = (const int*)d_in[1];
    const float* wts     = (const float*)d_in[2];
    float*       out     = (float*)d_out;
    unsigned int* cm     = (unsigned int*)d_ws;

    const long long n_rows = (long long)in_sizes[0] / CLS;

    hipMemsetAsync(cm, 0, CLS * CLS * sizeof(unsigned int), stream);
    cm_hist_kernel<<<HIST_BLOCKS, HIST_THREADS, 0, stream>>>(inputs, targets, wts, cm, n_rows);
    macro_score_kernel<<<1, 64, 0, stream>>>(cm, wts, out);
}